// Round 1
// baseline (114.310 us; speedup 1.0000x reference)
//
#include <hip/hip_runtime.h>

typedef unsigned short ushort_t;
typedef unsigned int uint_t;

#define HH 128
#define WW 128
#define CIN 128    // total input channels
#define CHALF 64   // channels per half
#define COUT 128   // total output channels
#define K2 9
#define KTOT 576   // 64 * 9
#define KC 192     // K elems per chunk (k = 3 taps x 64 ch)
#define LDK 200    // padded LDS row length (elems)

typedef __attribute__((ext_vector_type(8))) short bf16x8;
typedef __attribute__((ext_vector_type(4))) float f32x4;

static __device__ __forceinline__ ushort_t f2bf(float f) {
  union { float f; uint_t u; } x; x.f = f;
  uint_t u = x.u;
  return (ushort_t)((u + 0x7FFFu + ((u >> 16) & 1u)) >> 16);
}

static __device__ __forceinline__ int imin(int a, int b) { return a < b ? a : b; }
static __device__ __forceinline__ int imax(int a, int b) { return a > b ? a : b; }

// K0: weight (64,64,3,3) fp32 -> bf16 [o][kk], kk = k*64 + c
__global__ void prep_weight(const float* __restrict__ w, ushort_t* __restrict__ wbf) {
  int i = blockIdx.x * 256 + threadIdx.x;
  if (i >= 64 * KTOT) return;
  int o = i / KTOT, kk = i % KTOT;
  int k = kk >> 6, c = kk & 63;
  wbf[i] = f2bf(w[(o * 64 + c) * 9 + k]);
}

// K1: x BCHW -> NHWC (x_t[b][y][x][c])
__global__ void transpose_nchw_nhwc(const float* __restrict__ in, float* __restrict__ out) {
  __shared__ float tile[32][33];
  int b = blockIdx.z;
  int c0 = blockIdx.y * 32;
  int s0 = blockIdx.x * 32;
  int tx = threadIdx.x;   // 0..31
  int ty = threadIdx.y;   // 0..7
  const float* inb = in + (size_t)b * CIN * (HH * WW);
  float* outb = out + (size_t)b * (HH * WW) * CIN;
#pragma unroll
  for (int i = 0; i < 4; ++i) {
    int c = c0 + ty + 8 * i;
    tile[ty + 8 * i][tx] = inb[(size_t)c * (HH * WW) + s0 + tx];
  }
  __syncthreads();
#pragma unroll
  for (int i = 0; i < 4; ++i) {
    int s = s0 + ty + 8 * i;
    outb[(size_t)s * CIN + c0 + tx] = tile[tx][ty + 8 * i];
  }
}

// K2: offset passthrough -> second output
__global__ void copy_offset(const float4* __restrict__ in, float4* __restrict__ out, int n4) {
  int i = blockIdx.x * 256 + threadIdx.x;
  if (i < n4) out[i] = in[i];
}

// K3: main fused gather + MFMA GEMM.
// grid: 2048 blocks = 1024 spatial tiles x 2 halves; block 512 threads (8 waves).
// Block tile: 64 out-channels (one half) x 64 spatial positions, K = 576 in 3 chunks of 192.
__global__ __launch_bounds__(512)
void deform_main(const float* __restrict__ xt, const float* __restrict__ off,
                 const ushort_t* __restrict__ wbf, const float* __restrict__ bias,
                 float* __restrict__ out) {
  __shared__ __align__(16) ushort_t Alds[64 * LDK];  // weight [o][kk_local]
  __shared__ __align__(16) ushort_t Blds[64 * LDK];  // val    [p][kk_local]
  __shared__ __align__(16) float mw[KC * 4];         // 4 corner weights per task
  __shared__ __align__(16) int   mi[KC * 4];         // 4 corner elem-offsets per task

  const int bid = blockIdx.x;
  const int h   = bid & 1;           // half
  const int t   = bid >> 1;          // 0..1023
  const int b   = t >> 8;            // batch
  const int rr  = t & 255;
  const int ho  = rr >> 1;
  const int wo0 = (rr & 1) << 6;

  const int tid = threadIdx.x;
  const int c   = tid & 63;          // channel lane (staging)
  const int wv  = tid >> 6;          // wave id 0..7

  // GEMM lane mapping
  const int l  = tid & 63;
  const int r  = l & 15;
  const int g  = l >> 4;
  const int ob = (wv & 1) * 32;      // o block (32 rows per wave)
  const int pb = (wv >> 1) * 16;     // p block (16 cols per wave)

  f32x4 acc0 = {0.f, 0.f, 0.f, 0.f};
  f32x4 acc1 = {0.f, 0.f, 0.f, 0.f};

  const float* xth = xt + h * CHALF + c;

  for (int kc = 0; kc < 3; ++kc) {
    __syncthreads();  // protect LDS reuse vs previous chunk's GEMM reads

    // stage A chunk: 64 rows x 192 ushorts, 16B per thread-iter
    for (int i = tid; i < 64 * KC / 8; i += 512) {
      int row = i / 24, c8 = i % 24;
      uint4 v = *(const uint4*)&wbf[row * KTOT + kc * KC + c8 * 8];
      *(uint4*)&Alds[row * LDK + c8 * 8] = v;
    }

    // meta: 192 tasks = 3 taps x 64 positions
    if (tid < KC) {
      int k  = kc * 3 + (tid >> 6);
      int p  = tid & 63;
      int ky = k / 3, kx = k % 3;
      int wo = wo0 + p;
      float dy = off[((b * 18 + 2 * k) * HH + ho) * WW + wo];
      float dx = off[((b * 18 + 2 * k + 1) * HH + ho) * WW + wo];
      float py = dy + (float)(ky + ho - 1);
      float px = dx + (float)(kx + wo - 1);
      float y0f = floorf(py), x0f = floorf(px);
      float ly = py - y0f, lx = px - x0f;
      int y0 = (int)y0f, x0 = (int)x0f;
      int y1 = y0 + 1, x1 = x0 + 1;
      float wy0 = 1.f - ly, wx0 = 1.f - lx;
      bool vy0 = (y0 >= 0) & (y0 < HH), vy1 = (y1 >= 0) & (y1 < HH);
      bool vx0 = (x0 >= 0) & (x0 < WW), vx1 = (x1 >= 0) & (x1 < WW);
      int y0c = imin(imax(y0, 0), HH - 1), y1c = imin(imax(y1, 0), HH - 1);
      int x0c = imin(imax(x0, 0), WW - 1), x1c = imin(imax(x1, 0), WW - 1);
      float f00 = (vy0 && vx0) ? wy0 * wx0 : 0.f;
      float f01 = (vy0 && vx1) ? wy0 * lx  : 0.f;
      float f10 = (vy1 && vx0) ? ly  * wx0 : 0.f;
      float f11 = (vy1 && vx1) ? ly  * lx  : 0.f;
      int base = b * HH * WW;
      mi[tid * 4 + 0] = (base + y0c * WW + x0c) * CIN;
      mi[tid * 4 + 1] = (base + y0c * WW + x1c) * CIN;
      mi[tid * 4 + 2] = (base + y1c * WW + x0c) * CIN;
      mi[tid * 4 + 3] = (base + y1c * WW + x1c) * CIN;
      mw[tid * 4 + 0] = f00;
      mw[tid * 4 + 1] = f01;
      mw[tid * 4 + 2] = f10;
      mw[tid * 4 + 3] = f11;
    }
    __syncthreads();

    // stage B: gather + bilinear, 192 tasks / 8 waves = 24 per wave, lane = channel
    for (int j = 0; j < 24; ++j) {
      int tloc = wv + 8 * j;
      int kl = tloc >> 6;   // local tap 0..2
      int p  = tloc & 63;
      float4 w4 = *(const float4*)&mw[tloc * 4];
      int4   i4 = *(const int4*)&mi[tloc * 4];
      float v = w4.x * xth[i4.x] + w4.y * xth[i4.y]
              + w4.z * xth[i4.z] + w4.w * xth[i4.w];
      Blds[p * LDK + kl * 64 + c] = f2bf(v);
    }
    __syncthreads();

    // GEMM chunk: 6 K-steps of 32
#pragma unroll
    for (int ks = 0; ks < 6; ++ks) {
      int kk = ks * 32 + g * 8;
      bf16x8 a0 = *(const bf16x8*)&Alds[(ob + r) * LDK + kk];
      bf16x8 a1 = *(const bf16x8*)&Alds[(ob + 16 + r) * LDK + kk];
      bf16x8 bb = *(const bf16x8*)&Blds[(pb + r) * LDK + kk];
      acc0 = __builtin_amdgcn_mfma_f32_16x16x32_bf16(a0, bb, acc0, 0, 0, 0);
      acc1 = __builtin_amdgcn_mfma_f32_16x16x32_bf16(a1, bb, acc1, 0, 0, 0);
    }
  }

  // epilogue: D col = lane&15 (pos), row = 4*(lane>>4) + reg (o)
  int p  = pb + r;
  int wo = wo0 + p;
#pragma unroll
  for (int q = 0; q < 4; ++q) {
    int o0 = ob + 4 * g + q;
    int o1 = o0 + 16;
    out[((size_t)(b * COUT + h * CHALF + o0) * HH + ho) * WW + wo] = acc0[q] + bias[o0];
    out[((size_t)(b * COUT + h * CHALF + o1) * HH + ho) * WW + wo] = acc1[q] + bias[o1];
  }
}

extern "C" void kernel_launch(void* const* d_in, const int* in_sizes, int n_in,
                              void* d_out, int out_size, void* d_ws, size_t ws_size,
                              hipStream_t stream) {
  const float* x      = (const float*)d_in[0];  // (4,128,128,128)
  const float* offset = (const float*)d_in[1];  // (4,18,128,128)
  const float* weight = (const float*)d_in[2];  // (64,64,3,3)
  const float* bias   = (const float*)d_in[3];  // (64,)
  float* out = (float*)d_out;

  const size_t xt_elems = (size_t)4 * HH * WW * CIN;        // 8,388,608
  float* xt = (float*)d_ws;
  ushort_t* wbf = (ushort_t*)((char*)d_ws + xt_elems * sizeof(float));

  // K0: weight prep
  prep_weight<<<(64 * KTOT + 255) / 256, 256, 0, stream>>>(weight, wbf);

  // K1: transpose x to NHWC
  transpose_nchw_nhwc<<<dim3(512, 4, 4), dim3(32, 8), 0, stream>>>(x, xt);

  // K2: offset passthrough (second tuple output)
  const int off_elems = 4 * 18 * HH * WW;                   // 1,179,648
  copy_offset<<<(off_elems / 4 + 255) / 256, 256, 0, stream>>>(
      (const float4*)offset, (float4*)(out + xt_elems), off_elems / 4);

  // K3: main
  deform_main<<<2048, 512, 0, stream>>>(xt, offset, wbf, bias, out);
}

// Round 2
// 87.139 us; speedup vs baseline: 1.3118x; 1.3118x over previous
//
#include <hip/hip_runtime.h>
#include <hip/hip_bf16.h>

typedef unsigned short ushort_t;
typedef unsigned int uint_t;

#define HH 128
#define WW 128
#define CIN 128    // total input channels
#define CHALF 64   // channels per half
#define COUT 128   // total output channels
#define K2 9
#define KTOT 576   // 64 * 9
#define KC 192     // K elems per chunk (k = 3 taps x 64 ch)
#define LDK 200    // padded LDS row length (elems); 400B = 25*16B (odd) for b128 reads

typedef __attribute__((ext_vector_type(8))) short bf16x8;
typedef __attribute__((ext_vector_type(4))) float f32x4;

static __device__ __forceinline__ ushort_t f2bf(float f) {
  union { float f; uint_t u; } x; x.f = f;
  uint_t u = x.u;
  return (ushort_t)((u + 0x7FFFu + ((u >> 16) & 1u)) >> 16);
}

static __device__ __forceinline__ int imin(int a, int b) { return a < b ? a : b; }
static __device__ __forceinline__ int imax(int a, int b) { return a > b ? a : b; }

// K0: weight (64,64,3,3) fp32 -> bf16 [o][kk], kk = k*64 + c
__global__ void prep_weight(const float* __restrict__ w, ushort_t* __restrict__ wbf) {
  int i = blockIdx.x * 256 + threadIdx.x;
  if (i >= 64 * KTOT) return;
  int o = i / KTOT, kk = i % KTOT;
  int k = kk >> 6, c = kk & 63;
  wbf[i] = f2bf(w[(o * 64 + c) * 9 + k]);
}

// K1: x BCHW -> NHWC (x_t[b][y][x][c])
__global__ void transpose_nchw_nhwc(const float* __restrict__ in, float* __restrict__ out) {
  __shared__ float tile[32][33];
  int b = blockIdx.z;
  int c0 = blockIdx.y * 32;
  int s0 = blockIdx.x * 32;
  int tx = threadIdx.x;   // 0..31
  int ty = threadIdx.y;   // 0..7
  const float* inb = in + (size_t)b * CIN * (HH * WW);
  float* outb = out + (size_t)b * (HH * WW) * CIN;
#pragma unroll
  for (int i = 0; i < 4; ++i) {
    int c = c0 + ty + 8 * i;
    tile[ty + 8 * i][tx] = inb[(size_t)c * (HH * WW) + s0 + tx];
  }
  __syncthreads();
#pragma unroll
  for (int i = 0; i < 4; ++i) {
    int s = s0 + ty + 8 * i;
    outb[(size_t)s * CIN + c0 + tx] = tile[tx][ty + 8 * i];
  }
}

// K2: offset passthrough -> second output
__global__ void copy_offset(const float4* __restrict__ in, float4* __restrict__ out, int n4) {
  int i = blockIdx.x * 256 + threadIdx.x;
  if (i < n4) out[i] = in[i];
}

// K3: main fused gather + MFMA GEMM.
// grid: 2048 blocks = 1024 spatial tiles x 2 halves; block 512 threads (8 waves).
// Block tile: 64 out-channels (one half) x 64 spatial positions, K = 576 in 3 chunks of 192.
__global__ __launch_bounds__(512)
void deform_main(const float* __restrict__ xt, const float* __restrict__ off,
                 const ushort_t* __restrict__ wbf, const float* __restrict__ bias,
                 float* __restrict__ out) {
  __shared__ __align__(16) ushort_t Alds[64 * LDK];  // weight [o][kk_local]
  __shared__ __align__(16) ushort_t Blds[64 * LDK];  // val    [p][kk_local]
  __shared__ __align__(16) float mw[KC * 4];         // 4 corner weights per task
  __shared__ __align__(16) int   mi[KC * 4];         // 4 corner BYTE offsets per task

  const int bid = blockIdx.x;
  const int h   = bid & 1;           // half
  const int t0  = bid >> 1;          // 0..1023
  const int b   = t0 >> 8;           // batch
  const int rr  = t0 & 255;
  const int ho  = rr >> 1;
  const int wo0 = (rr & 1) << 6;

  const int tid = threadIdx.x;
  const int wv  = tid >> 6;          // wave id 0..7

  // GEMM lane mapping
  const int l  = tid & 63;
  const int r  = l & 15;
  const int g  = l >> 4;
  const int ob = (wv & 1) * 32;      // o block (32 rows per wave)
  const int pb = (wv >> 1) * 16;     // p block (16 cols per wave)

  f32x4 acc0 = {0.f, 0.f, 0.f, 0.f};
  f32x4 acc1 = {0.f, 0.f, 0.f, 0.f};

  const char* xbase = (const char*)xt;   // byte offsets in mi include batch/spatial/half

  for (int kc = 0; kc < 3; ++kc) {
    __syncthreads();  // protect LDS reuse vs previous chunk's GEMM reads

    // stage A chunk: 64 rows x 192 ushorts, 16B per thread-iter
    for (int i = tid; i < 64 * KC / 8; i += 512) {
      int row = i / 24, c8 = i % 24;
      uint4 v = *(const uint4*)&wbf[row * KTOT + kc * KC + c8 * 8];
      *(uint4*)&Alds[row * LDK + c8 * 8] = v;
    }

    // meta: 192 tasks = 3 taps x 64 positions
    if (tid < KC) {
      int k  = kc * 3 + (tid >> 6);
      int p  = tid & 63;
      int ky = k / 3, kx = k % 3;
      int wo = wo0 + p;
      float dy = off[((b * 18 + 2 * k) * HH + ho) * WW + wo];
      float dx = off[((b * 18 + 2 * k + 1) * HH + ho) * WW + wo];
      float py = dy + (float)(ky + ho - 1);
      float px = dx + (float)(kx + wo - 1);
      float y0f = floorf(py), x0f = floorf(px);
      float ly = py - y0f, lx = px - x0f;
      int y0 = (int)y0f, x0 = (int)x0f;
      int y1 = y0 + 1, x1 = x0 + 1;
      float wy0 = 1.f - ly, wx0 = 1.f - lx;
      bool vy0 = (y0 >= 0) & (y0 < HH), vy1 = (y1 >= 0) & (y1 < HH);
      bool vx0 = (x0 >= 0) & (x0 < WW), vx1 = (x1 >= 0) & (x1 < WW);
      int y0c = imin(imax(y0, 0), HH - 1), y1c = imin(imax(y1, 0), HH - 1);
      int x0c = imin(imax(x0, 0), WW - 1), x1c = imin(imax(x1, 0), WW - 1);
      float f00 = (vy0 && vx0) ? wy0 * wx0 : 0.f;
      float f01 = (vy0 && vx1) ? wy0 * lx  : 0.f;
      float f10 = (vy1 && vx0) ? ly  * wx0 : 0.f;
      float f11 = (vy1 && vx1) ? ly  * lx  : 0.f;
      int base = b * HH * WW;
      int hb   = h * CHALF * 4;           // byte offset of this half's channels
      mi[tid * 4 + 0] = (base + y0c * WW + x0c) * (CIN * 4) + hb;
      mi[tid * 4 + 1] = (base + y0c * WW + x1c) * (CIN * 4) + hb;
      mi[tid * 4 + 2] = (base + y1c * WW + x0c) * (CIN * 4) + hb;
      mi[tid * 4 + 3] = (base + y1c * WW + x1c) * (CIN * 4) + hb;
      mw[tid * 4 + 0] = f00;
      mw[tid * 4 + 1] = f01;
      mw[tid * 4 + 2] = f10;
      mw[tid * 4 + 3] = f11;
    }
    __syncthreads();

    // stage B: gather + bilinear, float4-vectorized.
    // 3072 items/chunk = 192 tasks x 16 channel-quarters; 6 per thread.
    // 16-lane group = one task; lane's quarter q -> channels 4q..4q+3 (coalesced 256B).
#pragma unroll
    for (int j = 0; j < 6; ++j) {
      int item = tid + 512 * j;
      int t = item >> 4;        // task 0..191
      int q = item & 15;        // channel quarter
      int kl = t >> 6;          // local tap 0..2
      int p  = t & 63;          // position
      int4   i4 = *(const int4*)&mi[t * 4];
      float4 w4 = *(const float4*)&mw[t * 4];
      int qb = q << 4;
      float4 v0 = *(const float4*)(xbase + (i4.x + qb));
      float4 v1 = *(const float4*)(xbase + (i4.y + qb));
      float4 v2 = *(const float4*)(xbase + (i4.z + qb));
      float4 v3 = *(const float4*)(xbase + (i4.w + qb));
      float4 v;
      v.x = w4.x * v0.x + w4.y * v1.x + w4.z * v2.x + w4.w * v3.x;
      v.y = w4.x * v0.y + w4.y * v1.y + w4.z * v2.y + w4.w * v3.y;
      v.z = w4.x * v0.z + w4.y * v1.z + w4.z * v2.z + w4.w * v3.z;
      v.w = w4.x * v0.w + w4.y * v1.w + w4.z * v2.w + w4.w * v3.w;
      union { __hip_bfloat162 h2[2]; uint2 u2; } pk;
      pk.h2[0] = __float22bfloat162_rn(make_float2(v.x, v.y));
      pk.h2[1] = __float22bfloat162_rn(make_float2(v.z, v.w));
      *(uint2*)&Blds[p * LDK + kl * 64 + q * 4] = pk.u2;
    }
    __syncthreads();

    // GEMM chunk: 6 K-steps of 32
#pragma unroll
    for (int ks = 0; ks < 6; ++ks) {
      int kk = ks * 32 + g * 8;
      bf16x8 a0 = *(const bf16x8*)&Alds[(ob + r) * LDK + kk];
      bf16x8 a1 = *(const bf16x8*)&Alds[(ob + 16 + r) * LDK + kk];
      bf16x8 bb = *(const bf16x8*)&Blds[(pb + r) * LDK + kk];
      acc0 = __builtin_amdgcn_mfma_f32_16x16x32_bf16(a0, bb, acc0, 0, 0, 0);
      acc1 = __builtin_amdgcn_mfma_f32_16x16x32_bf16(a1, bb, acc1, 0, 0, 0);
    }
  }

  // epilogue: D col = lane&15 (pos), row = 4*(lane>>4) + reg (o)
  int p  = pb + r;
  int wo = wo0 + p;
#pragma unroll
  for (int q = 0; q < 4; ++q) {
    int o0 = ob + 4 * g + q;
    int o1 = o0 + 16;
    out[((size_t)(b * COUT + h * CHALF + o0) * HH + ho) * WW + wo] = acc0[q] + bias[o0];
    out[((size_t)(b * COUT + h * CHALF + o1) * HH + ho) * WW + wo] = acc1[q] + bias[o1];
  }
}

extern "C" void kernel_launch(void* const* d_in, const int* in_sizes, int n_in,
                              void* d_out, int out_size, void* d_ws, size_t ws_size,
                              hipStream_t stream) {
  const float* x      = (const float*)d_in[0];  // (4,128,128,128)
  const float* offset = (const float*)d_in[1];  // (4,18,128,128)
  const float* weight = (const float*)d_in[2];  // (64,64,3,3)
  const float* bias   = (const float*)d_in[3];  // (64,)
  float* out = (float*)d_out;

  const size_t xt_elems = (size_t)4 * HH * WW * CIN;        // 8,388,608
  float* xt = (float*)d_ws;
  ushort_t* wbf = (ushort_t*)((char*)d_ws + xt_elems * sizeof(float));

  // K0: weight prep
  prep_weight<<<(64 * KTOT + 255) / 256, 256, 0, stream>>>(weight, wbf);

  // K1: transpose x to NHWC
  transpose_nchw_nhwc<<<dim3(512, 4, 4), dim3(32, 8), 0, stream>>>(x, xt);

  // K2: offset passthrough (second tuple output)
  const int off_elems = 4 * 18 * HH * WW;                   // 1,179,648
  copy_offset<<<(off_elems / 4 + 255) / 256, 256, 0, stream>>>(
      (const float4*)offset, (float4*)(out + xt_elems), off_elems / 4);

  // K3: main
  deform_main<<<2048, 512, 0, stream>>>(xt, offset, wbf, bias, out);
}

// Round 3
// 79.687 us; speedup vs baseline: 1.4345x; 1.0935x over previous
//
#include <hip/hip_runtime.h>
#include <hip/hip_bf16.h>

typedef unsigned short ushort_t;
typedef unsigned int uint_t;

#define HH 128
#define WW 128
#define CIN 128    // total input channels
#define CHALF 64
#define COUT 128
#define KTOT 576   // 64 ch * 9 taps (weight K layout)
#define BP 32      // positions per block
#define LDA 72     // A row stride, elems (64 + 8 pad)
#define LDB 136    // B row stride, elems (128 + 8 pad)
#define ASZ (64 * LDA)   // 4608 elems
#define BSZ (BP * LDB)   // 4352 elems
#define NTASK (9 * BP)   // 288 meta tasks (tap x position)

typedef __attribute__((ext_vector_type(8))) short bf16x8;
typedef __attribute__((ext_vector_type(4))) float f32x4;

static __device__ __forceinline__ ushort_t f2bf(float f) {
  union { float f; uint_t u; } x; x.f = f;
  uint_t u = x.u;
  return (ushort_t)((u + 0x7FFFu + ((u >> 16) & 1u)) >> 16);
}

static __device__ __forceinline__ int imin(int a, int b) { return a < b ? a : b; }
static __device__ __forceinline__ int imax(int a, int b) { return a > b ? a : b; }

// K0: weight (64,64,3,3) fp32 -> bf16 [o][kk], kk = k*64 + c
__global__ void prep_weight(const float* __restrict__ w, ushort_t* __restrict__ wbf) {
  int i = blockIdx.x * 256 + threadIdx.x;
  if (i >= 64 * KTOT) return;
  int o = i / KTOT, kk = i % KTOT;
  int k = kk >> 6, c = kk & 63;
  wbf[i] = f2bf(w[(o * 64 + c) * 9 + k]);
}

// K1: x BCHW -> NHWC (x_t[b][y][x][c])
__global__ void transpose_nchw_nhwc(const float* __restrict__ in, float* __restrict__ out) {
  __shared__ float tile[32][33];
  int b = blockIdx.z;
  int c0 = blockIdx.y * 32;
  int s0 = blockIdx.x * 32;
  int tx = threadIdx.x;
  int ty = threadIdx.y;
  const float* inb = in + (size_t)b * CIN * (HH * WW);
  float* outb = out + (size_t)b * (HH * WW) * CIN;
#pragma unroll
  for (int i = 0; i < 4; ++i) {
    int c = c0 + ty + 8 * i;
    tile[ty + 8 * i][tx] = inb[(size_t)c * (HH * WW) + s0 + tx];
  }
  __syncthreads();
#pragma unroll
  for (int i = 0; i < 4; ++i) {
    int s = s0 + ty + 8 * i;
    outb[(size_t)s * CIN + c0 + tx] = tile[tx][ty + 8 * i];
  }
}

// K2: offset passthrough -> second output
__global__ void copy_offset(const float4* __restrict__ in, float4* __restrict__ out, int n4) {
  int i = blockIdx.x * 256 + threadIdx.x;
  if (i < n4) out[i] = in[i];
}

// K3: fused gather + MFMA GEMM, halves merged, per-tap double-buffered pipeline.
// grid: 2048 blocks = 4 batch x 512 tiles of 32 positions; block 512 threads (8 waves).
// Block output: 128 out-ch x 32 pos. K = 9 taps x 64 ch per half; wave's o-block
// selects which half's val channels feed its B operand.
__global__ __launch_bounds__(512, 4)
void deform_main(const float* __restrict__ xt, const float* __restrict__ off,
                 const ushort_t* __restrict__ wbf, const float* __restrict__ bias,
                 float* __restrict__ out) {
  __shared__ __align__(16) ushort_t Alds[2 * ASZ];   // weight [o(64)][c] x2 buf
  __shared__ __align__(16) ushort_t Blds[2 * BSZ];   // val    [p(32)][c(128)] x2 buf
  __shared__ __align__(16) int   mi[NTASK * 4];      // corner byte offsets
  __shared__ __align__(16) float mw[NTASK * 4];      // corner weights

  // XCD-aware swizzle (2048 % 8 == 0 -> simple bijective form):
  // XCD k processes a contiguous range of 256 tiles (~4MB x_t slab -> L2-resident).
  const int n  = blockIdx.x;
  const int l  = (n & 7) * 256 + (n >> 3);
  const int b  = l >> 9;            // batch
  const int rr = l & 511;
  const int ho = rr >> 2;
  const int wo0 = (rr & 3) << 5;    // 4 tiles of 32 per row

  const int tid  = threadIdx.x;
  const int wv   = tid >> 6;
  const int lane = tid & 63;
  const int r    = lane & 15;
  const int g    = lane >> 4;
  const int ob   = (wv & 3) << 5;   // out-ch block: 0,32,64,96
  const int pb   = (wv >> 2) << 4;  // pos block: 0,16
  const int arow = ob & 32;         // weight row base (weight shared by halves)
  const int cb   = ob & 64;         // B channel base: half select

  // ---- meta for all 9 taps x 32 positions ----
  if (tid < NTASK) {
    int k = tid >> 5, p = tid & 31;
    int ky = k / 3, kx = k % 3;
    int wo = wo0 + p;
    float dy = off[((b * 18 + 2 * k) * HH + ho) * WW + wo];
    float dx = off[((b * 18 + 2 * k + 1) * HH + ho) * WW + wo];
    float py = dy + (float)(ky + ho - 1);
    float px = dx + (float)(kx + wo - 1);
    float y0f = floorf(py), x0f = floorf(px);
    float ly = py - y0f, lx = px - x0f;
    int y0 = (int)y0f, x0 = (int)x0f;
    int y1 = y0 + 1, x1 = x0 + 1;
    float wy0 = 1.f - ly, wx0 = 1.f - lx;
    bool vy0 = (y0 >= 0) & (y0 < HH), vy1 = (y1 >= 0) & (y1 < HH);
    bool vx0 = (x0 >= 0) & (x0 < WW), vx1 = (x1 >= 0) & (x1 < WW);
    int y0c = imin(imax(y0, 0), HH - 1), y1c = imin(imax(y1, 0), HH - 1);
    int x0c = imin(imax(x0, 0), WW - 1), x1c = imin(imax(x1, 0), WW - 1);
    int base = b * HH * WW;
    mi[tid * 4 + 0] = (base + y0c * WW + x0c) * (CIN * 4);
    mi[tid * 4 + 1] = (base + y0c * WW + x1c) * (CIN * 4);
    mi[tid * 4 + 2] = (base + y1c * WW + x0c) * (CIN * 4);
    mi[tid * 4 + 3] = (base + y1c * WW + x1c) * (CIN * 4);
    mw[tid * 4 + 0] = (vy0 && vx0) ? wy0 * wx0 : 0.f;
    mw[tid * 4 + 1] = (vy0 && vx1) ? wy0 * lx  : 0.f;
    mw[tid * 4 + 2] = (vy1 && vx0) ? ly  * wx0 : 0.f;
    mw[tid * 4 + 3] = (vy1 && vx1) ? ly  * lx  : 0.f;
  }

  // ---- staging thread mappings ----
  const int ao  = tid >> 3;             // A: out-row 0..63
  const int ac8 = (tid & 7) << 3;       // A: 8-elem chunk
  const ushort_t* wsrc = wbf + ao * KTOT + ac8;
  const int q  = tid & 31;              // B: channel quarter 0..31 (4 ch each)
  const int p0 = tid >> 5;              // B: item0 position 0..15 (item1 = +16)
  const char* xq = (const char*)xt + (q << 4);

  // in-flight staging registers (T14: issue early, commit after MFMA)
  uint4  aval;
  float4 c00, c01, c02, c03, c10, c11, c12, c13;

  __syncthreads();  // meta ready

  // ---- prologue: stage tap 0 into buffer 0 ----
  {
    aval = *(const uint4*)(wsrc + 0 * 64);
    int4 i0 = *(const int4*)&mi[p0 * 4];
    int4 i1 = *(const int4*)&mi[(p0 + 16) * 4];
    c00 = *(const float4*)(xq + i0.x); c01 = *(const float4*)(xq + i0.y);
    c02 = *(const float4*)(xq + i0.z); c03 = *(const float4*)(xq + i0.w);
    c10 = *(const float4*)(xq + i1.x); c11 = *(const float4*)(xq + i1.y);
    c12 = *(const float4*)(xq + i1.z); c13 = *(const float4*)(xq + i1.w);
    *(uint4*)&Alds[ao * LDA + ac8] = aval;
    float4 w0 = *(const float4*)&mw[p0 * 4];
    float4 w1 = *(const float4*)&mw[(p0 + 16) * 4];
    float4 v0, v1;
    v0.x = w0.x*c00.x + w0.y*c01.x + w0.z*c02.x + w0.w*c03.x;
    v0.y = w0.x*c00.y + w0.y*c01.y + w0.z*c02.y + w0.w*c03.y;
    v0.z = w0.x*c00.z + w0.y*c01.z + w0.z*c02.z + w0.w*c03.z;
    v0.w = w0.x*c00.w + w0.y*c01.w + w0.z*c02.w + w0.w*c03.w;
    v1.x = w1.x*c10.x + w1.y*c11.x + w1.z*c12.x + w1.w*c13.x;
    v1.y = w1.x*c10.y + w1.y*c11.y + w1.z*c12.y + w1.w*c13.y;
    v1.z = w1.x*c10.z + w1.y*c11.z + w1.z*c12.z + w1.w*c13.z;
    v1.w = w1.x*c10.w + w1.y*c11.w + w1.z*c12.w + w1.w*c13.w;
    union { __hip_bfloat162 h2[2]; uint2 u2; } pk0, pk1;
    pk0.h2[0] = __float22bfloat162_rn(make_float2(v0.x, v0.y));
    pk0.h2[1] = __float22bfloat162_rn(make_float2(v0.z, v0.w));
    pk1.h2[0] = __float22bfloat162_rn(make_float2(v1.x, v1.y));
    pk1.h2[1] = __float22bfloat162_rn(make_float2(v1.z, v1.w));
    *(uint2*)&Blds[p0 * LDB + q * 4] = pk0.u2;
    *(uint2*)&Blds[(p0 + 16) * LDB + q * 4] = pk1.u2;
  }
  __syncthreads();

  f32x4 acc0 = {0.f, 0.f, 0.f, 0.f};
  f32x4 acc1 = {0.f, 0.f, 0.f, 0.f};

  // ---- main loop: 9 taps, double-buffered ----
  for (int t = 0; t < 9; ++t) {
    const int bs = t & 1, ns = bs ^ 1;
    const ushort_t* Ab = &Alds[bs * ASZ];
    const ushort_t* Bb = &Blds[bs * BSZ];

    // issue next tap's loads (global latency hides under MFMA below)
    if (t < 8) {
      int k = t + 1;
      aval = *(const uint4*)(wsrc + k * 64);
      int t0 = k * 32 + p0, t1 = t0 + 16;
      int4 i0 = *(const int4*)&mi[t0 * 4];
      int4 i1 = *(const int4*)&mi[t1 * 4];
      c00 = *(const float4*)(xq + i0.x); c01 = *(const float4*)(xq + i0.y);
      c02 = *(const float4*)(xq + i0.z); c03 = *(const float4*)(xq + i0.w);
      c10 = *(const float4*)(xq + i1.x); c11 = *(const float4*)(xq + i1.y);
      c12 = *(const float4*)(xq + i1.z); c13 = *(const float4*)(xq + i1.w);
    }

    // GEMM on current buffer: K=64 in 2 steps of 32
#pragma unroll
    for (int ks = 0; ks < 2; ++ks) {
      int kk = ks * 32 + g * 8;
      bf16x8 a0 = *(const bf16x8*)&Ab[(arow + r) * LDA + kk];
      bf16x8 a1 = *(const bf16x8*)&Ab[(arow + 16 + r) * LDA + kk];
      bf16x8 bbf = *(const bf16x8*)&Bb[(pb + r) * LDB + cb + kk];
      acc0 = __builtin_amdgcn_mfma_f32_16x16x32_bf16(a0, bbf, acc0, 0, 0, 0);
      acc1 = __builtin_amdgcn_mfma_f32_16x16x32_bf16(a1, bbf, acc1, 0, 0, 0);
    }

    // commit next tap into the other buffer
    if (t < 8) {
      int k = t + 1;
      *(uint4*)&Alds[ns * ASZ + ao * LDA + ac8] = aval;
      int t0 = k * 32 + p0, t1 = t0 + 16;
      float4 w0 = *(const float4*)&mw[t0 * 4];
      float4 w1 = *(const float4*)&mw[t1 * 4];
      float4 v0, v1;
      v0.x = w0.x*c00.x + w0.y*c01.x + w0.z*c02.x + w0.w*c03.x;
      v0.y = w0.x*c00.y + w0.y*c01.y + w0.z*c02.y + w0.w*c03.y;
      v0.z = w0.x*c00.z + w0.y*c01.z + w0.z*c02.z + w0.w*c03.z;
      v0.w = w0.x*c00.w + w0.y*c01.w + w0.z*c02.w + w0.w*c03.w;
      v1.x = w1.x*c10.x + w1.y*c11.x + w1.z*c12.x + w1.w*c13.x;
      v1.y = w1.x*c10.y + w1.y*c11.y + w1.z*c12.y + w1.w*c13.y;
      v1.z = w1.x*c10.z + w1.y*c11.z + w1.z*c12.z + w1.w*c13.z;
      v1.w = w1.x*c10.w + w1.y*c11.w + w1.z*c12.w + w1.w*c13.w;
      union { __hip_bfloat162 h2[2]; uint2 u2; } pk0, pk1;
      pk0.h2[0] = __float22bfloat162_rn(make_float2(v0.x, v0.y));
      pk0.h2[1] = __float22bfloat162_rn(make_float2(v0.z, v0.w));
      pk1.h2[0] = __float22bfloat162_rn(make_float2(v1.x, v1.y));
      pk1.h2[1] = __float22bfloat162_rn(make_float2(v1.z, v1.w));
      *(uint2*)&Blds[ns * BSZ + p0 * LDB + q * 4] = pk0.u2;
      *(uint2*)&Blds[ns * BSZ + (p0 + 16) * LDB + q * 4] = pk1.u2;
    }
    __syncthreads();
  }

  // ---- epilogue: D col = lane&15 (pos), row = 4*(lane>>4)+reg (o) ----
  int wo = wo0 + pb + r;
#pragma unroll
  for (int qq = 0; qq < 4; ++qq) {
    int o0 = ob + 4 * g + qq;
    int o1 = o0 + 16;
    out[((size_t)(b * COUT + o0) * HH + ho) * WW + wo] = acc0[qq] + bias[o0 & 63];
    out[((size_t)(b * COUT + o1) * HH + ho) * WW + wo] = acc1[qq] + bias[o1 & 63];
  }
}

extern "C" void kernel_launch(void* const* d_in, const int* in_sizes, int n_in,
                              void* d_out, int out_size, void* d_ws, size_t ws_size,
                              hipStream_t stream) {
  const float* x      = (const float*)d_in[0];  // (4,128,128,128)
  const float* offset = (const float*)d_in[1];  // (4,18,128,128)
  const float* weight = (const float*)d_in[2];  // (64,64,3,3)
  const float* bias   = (const float*)d_in[3];  // (64,)
  float* out = (float*)d_out;

  const size_t xt_elems = (size_t)4 * HH * WW * CIN;        // 8,388,608
  float* xt = (float*)d_ws;
  ushort_t* wbf = (ushort_t*)((char*)d_ws + xt_elems * sizeof(float));

  prep_weight<<<(64 * KTOT + 255) / 256, 256, 0, stream>>>(weight, wbf);
  transpose_nchw_nhwc<<<dim3(512, 4, 4), dim3(32, 8), 0, stream>>>(x, xt);

  const int off_elems = 4 * 18 * HH * WW;                   // 1,179,648
  copy_offset<<<(off_elems / 4 + 255) / 256, 256, 0, stream>>>(
      (const float4*)offset, (float4*)(out + xt_elems), off_elems / 4);

  deform_main<<<2048, 512, 0, stream>>>(xt, offset, wbf, bias, out);
}

// Round 4
// 58.360 us; speedup vs baseline: 1.9587x; 1.3654x over previous
//
#include <hip/hip_runtime.h>
#include <hip/hip_bf16.h>
#include <hip/hip_fp16.h>

typedef unsigned short ushort_t;
typedef unsigned int uint_t;

#define HH 128
#define WW 128
#define CIN 128
#define COUT 128
#define NPIX (HH * WW)          // 16384 pixels per batch
#define PIXB 256                // bytes per bf16 pixel (128 ch * 2B)
#define BP 32                   // positions per block
#define LDB 136                 // B row stride elems (128 + 8 pad)
#define ASZ 4096                // A buffer elems per tap (64 o x 64 c, swizzled)
#define BSZ (BP * LDB)          // 4352
#define NTASK (9 * BP)          // 288

typedef __attribute__((ext_vector_type(8))) short bf16x8;
typedef __attribute__((ext_vector_type(4))) float f32x4;

static __device__ __forceinline__ ushort_t f2bf(float f) {
  union { float f; uint_t u; } x; x.f = f;
  uint_t u = x.u;
  return (ushort_t)((u + 0x7FFFu + ((u >> 16) & 1u)) >> 16);
}
static __device__ __forceinline__ float bflo2f(uint_t u) {  // low bf16 -> f32
  union { uint_t u; float f; } x; x.u = u << 16; return x.f;
}
static __device__ __forceinline__ float bfhi2f(uint_t u) {  // high bf16 -> f32
  union { uint_t u; float f; } x; x.u = u & 0xFFFF0000u; return x.f;
}
static __device__ __forceinline__ float h2f(ushort_t us) {
  union { ushort_t u; __half h; } x; x.u = us; return __half2float(x.h);
}
static __device__ __forceinline__ int imin(int a, int b) { return a < b ? a : b; }
static __device__ __forceinline__ int imax(int a, int b) { return a > b ? a : b; }

// K0: weight (64,64,3,3) -> bf16, tap-major, XOR-swizzled:
// dest elem for (k,o,c): k*4096 + (((o*8 + (c>>3)) ^ (o&7)) * 8 + (c&7))
__global__ void prep_weight(const float* __restrict__ w, ushort_t* __restrict__ wbf) {
  int i = blockIdx.x * 256 + threadIdx.x;
  if (i >= 9 * 4096) return;
  int k = i >> 12, e = i & 4095;
  int gp = e >> 3, sub = e & 7;
  int o = gp >> 3;
  int c = (((gp & 7) ^ (o & 7)) << 3) | sub;
  wbf[i] = f2bf(w[(o * 64 + c) * 9 + k]);
}

// K1: x BCHW f32 -> NHWC bf16
__global__ void transpose_nchw_nhwc(const float* __restrict__ in, uint_t* __restrict__ out) {
  __shared__ float tile[32][33];
  int b = blockIdx.z;
  int c0 = blockIdx.y * 32;
  int s0 = blockIdx.x * 32;
  int tx = threadIdx.x;   // 0..31
  int ty = threadIdx.y;   // 0..7
  const float* inb = in + (size_t)b * CIN * NPIX;
  uint_t* outb = out + (size_t)b * NPIX * (CIN / 2);
#pragma unroll
  for (int i = 0; i < 4; ++i) {
    int c = c0 + ty + 8 * i;
    tile[ty + 8 * i][tx] = inb[(size_t)c * NPIX + s0 + tx];
  }
  __syncthreads();
  int idx = ty * 32 + tx;       // 0..255
  int u = idx & 15;             // ch pair
  int sl = idx >> 4;            // 0..15
#pragma unroll
  for (int i = 0; i < 2; ++i) {
    int s = sl + 16 * i;
    __hip_bfloat162 pk = __float22bfloat162_rn(
        make_float2(tile[2 * u][s], tile[2 * u + 1][s]));
    outb[(size_t)(s0 + s) * (CIN / 2) + (c0 >> 1) + u] = *(uint_t*)&pk;
  }
}

// K2: offset passthrough
__global__ void copy_offset(const float4* __restrict__ in, float4* __restrict__ out, int n4) {
  int i = blockIdx.x * 256 + threadIdx.x;
  if (i < n4) out[i] = in[i];
}

// K3: fused gather + MFMA. 2048 blocks x 512 thr. Tile: 128 o x 32 pos, 9 taps.
__global__ __launch_bounds__(512, 8)
void deform_main(const ushort_t* __restrict__ xtb, const float* __restrict__ off,
                 const ushort_t* __restrict__ wbf, const float* __restrict__ bias,
                 float* __restrict__ out) {
  __shared__ __align__(16) ushort_t Alds[2 * ASZ];   // weight, swizzled granules
  __shared__ __align__(16) ushort_t Blds[2 * BSZ];   // val [p][c]
  __shared__ __align__(16) uint4 meta[NTASK];        // u16 idx x4 | f16 w x4

  const int n  = blockIdx.x;
  const int l  = (n & 7) * 256 + (n >> 3);           // XCD swizzle (2048%8==0)
  const int b  = l >> 9;
  const int rr = l & 511;
  const int ho = rr >> 2;
  const int wo0 = (rr & 3) << 5;

  const int tid  = threadIdx.x;
  const int wv   = tid >> 6;
  const int lane = tid & 63;
  const int r    = lane & 15;
  const int g    = lane >> 4;
  const int ob   = (wv & 3) << 5;
  const int pb   = (wv >> 2) << 4;
  const int arow = ob & 32;
  const int cb   = ob & 64;

  // ---- meta: 9 taps x 32 positions, compact 16B/task ----
  if (tid < NTASK) {
    int k = tid >> 5, p = tid & 31;
    int ky = k / 3, kx = k % 3;
    int wo = wo0 + p;
    float dy = off[((b * 18 + 2 * k) * HH + ho) * WW + wo];
    float dx = off[((b * 18 + 2 * k + 1) * HH + ho) * WW + wo];
    float py = dy + (float)(ky + ho - 1);
    float px = dx + (float)(kx + wo - 1);
    float y0f = floorf(py), x0f = floorf(px);
    float ly = py - y0f, lx = px - x0f;
    int y0 = (int)y0f, x0 = (int)x0f;
    int y1 = y0 + 1, x1 = x0 + 1;
    float wy0 = 1.f - ly, wx0 = 1.f - lx;
    bool vy0 = (y0 >= 0) & (y0 < HH), vy1 = (y1 >= 0) & (y1 < HH);
    bool vx0 = (x0 >= 0) & (x0 < WW), vx1 = (x1 >= 0) & (x1 < WW);
    int y0c = imin(imax(y0, 0), HH - 1), y1c = imin(imax(y1, 0), HH - 1);
    int x0c = imin(imax(x0, 0), WW - 1), x1c = imin(imax(x1, 0), WW - 1);
    uint_t i00 = y0c * WW + x0c, i01 = y0c * WW + x1c;
    uint_t i10 = y1c * WW + x0c, i11 = y1c * WW + x1c;
    float f00 = (vy0 && vx0) ? wy0 * wx0 : 0.f;
    float f01 = (vy0 && vx1) ? wy0 * lx  : 0.f;
    float f10 = (vy1 && vx0) ? ly  * wx0 : 0.f;
    float f11 = (vy1 && vx1) ? ly  * lx  : 0.f;
    union { __half h; ushort_t u; } h00, h01, h10, h11;
    h00.h = __float2half_rn(f00); h01.h = __float2half_rn(f01);
    h10.h = __float2half_rn(f10); h11.h = __float2half_rn(f11);
    uint4 m;
    m.x = i00 | (i01 << 16);
    m.y = i10 | (i11 << 16);
    m.z = (uint_t)h00.u | ((uint_t)h01.u << 16);
    m.w = (uint_t)h10.u | ((uint_t)h11.u << 16);
    meta[tid] = m;
  }

  // gather mapping: one task (4 corners, 8 ch) per thread per tap
  const int q  = tid & 15;            // channel octet
  const int p0 = tid >> 4;            // position 0..31
  const char* xb = (const char*)xtb + (size_t)b * NPIX * PIXB + q * 16;

  // A gload mapping: thread copies 16B, pre-swizzled source is linear
  const char* asrc = (const char*)wbf + tid * 16;
  char* adst0 = (char*)Alds + wv * 1024;             // + bufsel*8192

  uint4 c0v, c1v, c2v, c3v;    // in-flight gather (one task)
  uint4 mreg;

  __syncthreads();  // meta ready

  // ---- prologue: tap 0 into buffer 0 ----
  {
    __builtin_amdgcn_global_load_lds(
        (const __attribute__((address_space(1))) uint_t*)asrc,
        (__attribute__((address_space(3))) uint_t*)adst0, 16, 0, 0);
    mreg = meta[p0];
    c0v = *(const uint4*)(xb + ((mreg.x & 0xFFFFu) << 8));
    c1v = *(const uint4*)(xb + ((mreg.x >> 16) << 8));
    c2v = *(const uint4*)(xb + ((mreg.y & 0xFFFFu) << 8));
    c3v = *(const uint4*)(xb + ((mreg.y >> 16) << 8));
    float w00 = h2f((ushort_t)mreg.z), w01 = h2f((ushort_t)(mreg.z >> 16));
    float w10 = h2f((ushort_t)mreg.w), w11 = h2f((ushort_t)(mreg.w >> 16));
    float va[8];
#pragma unroll
    for (int j = 0; j < 4; ++j) {
      uint_t u0 = ((const uint_t*)&c0v)[j], u1 = ((const uint_t*)&c1v)[j];
      uint_t u2 = ((const uint_t*)&c2v)[j], u3 = ((const uint_t*)&c3v)[j];
      va[2*j]   = w00*bflo2f(u0) + w01*bflo2f(u1) + w10*bflo2f(u2) + w11*bflo2f(u3);
      va[2*j+1] = w00*bfhi2f(u0) + w01*bfhi2f(u1) + w10*bfhi2f(u2) + w11*bfhi2f(u3);
    }
    union { __hip_bfloat162 h2v[4]; uint4 u4; } pk;
#pragma unroll
    for (int j = 0; j < 4; ++j)
      pk.h2v[j] = __float22bfloat162_rn(make_float2(va[2*j], va[2*j+1]));
    *(uint4*)&Blds[p0 * LDB + q * 8] = pk.u4;
  }
  __syncthreads();

  f32x4 acc0 = {0.f, 0.f, 0.f, 0.f};
  f32x4 acc1 = {0.f, 0.f, 0.f, 0.f};

  const int o0r = arow + r, o1r = arow + 16 + r;
  const int g0base = (o0r << 3) + g, g0m = o0r & 7;
  const int g1base = (o1r << 3) + g, g1m = o1r & 7;

  // ---- main loop: 9 taps, double-buffered, 1-tap lookahead ----
  for (int t = 0; t < 9; ++t) {
    const int bs = t & 1, ns = bs ^ 1;

    if (t < 8) {
      // async A[t+1] -> LDS(ns); gather[t+1] -> regs
      __builtin_amdgcn_global_load_lds(
          (const __attribute__((address_space(1))) uint_t*)(asrc + (t + 1) * 8192),
          (__attribute__((address_space(3))) uint_t*)(adst0 + ns * 8192), 16, 0, 0);
      mreg = meta[(t + 1) * 32 + p0];
      c0v = *(const uint4*)(xb + ((mreg.x & 0xFFFFu) << 8));
      c1v = *(const uint4*)(xb + ((mreg.x >> 16) << 8));
      c2v = *(const uint4*)(xb + ((mreg.y & 0xFFFFu) << 8));
      c3v = *(const uint4*)(xb + ((mreg.y >> 16) << 8));
    }

    // GEMM on current buffer: K=64, 2 steps of 32
    {
      const ushort_t* Ab = &Alds[bs * ASZ];
      const ushort_t* Bb = &Blds[bs * BSZ];
#pragma unroll
      for (int ks = 0; ks < 2; ++ks) {
        int kk = ks * 32 + g * 8;
        bf16x8 a0 = *(const bf16x8*)&Ab[(((g0base + (ks << 2)) ^ g0m) << 3)];
        bf16x8 a1 = *(const bf16x8*)&Ab[(((g1base + (ks << 2)) ^ g1m) << 3)];
        bf16x8 bbf = *(const bf16x8*)&Bb[(pb + r) * LDB + cb + kk];
        acc0 = __builtin_amdgcn_mfma_f32_16x16x32_bf16(a0, bbf, acc0, 0, 0, 0);
        acc1 = __builtin_amdgcn_mfma_f32_16x16x32_bf16(a1, bbf, acc1, 0, 0, 0);
      }
    }

    if (t < 8) {
      float w00 = h2f((ushort_t)mreg.z), w01 = h2f((ushort_t)(mreg.z >> 16));
      float w10 = h2f((ushort_t)mreg.w), w11 = h2f((ushort_t)(mreg.w >> 16));
      float va[8];
#pragma unroll
      for (int j = 0; j < 4; ++j) {
        uint_t u0 = ((const uint_t*)&c0v)[j], u1 = ((const uint_t*)&c1v)[j];
        uint_t u2 = ((const uint_t*)&c2v)[j], u3 = ((const uint_t*)&c3v)[j];
        va[2*j]   = w00*bflo2f(u0) + w01*bflo2f(u1) + w10*bflo2f(u2) + w11*bflo2f(u3);
        va[2*j+1] = w00*bfhi2f(u0) + w01*bfhi2f(u1) + w10*bfhi2f(u2) + w11*bfhi2f(u3);
      }
      union { __hip_bfloat162 h2v[4]; uint4 u4; } pk;
#pragma unroll
      for (int j = 0; j < 4; ++j)
        pk.h2v[j] = __float22bfloat162_rn(make_float2(va[2*j], va[2*j+1]));
      *(uint4*)&Blds[ns * BSZ + p0 * LDB + q * 8] = pk.u4;
    }
    __syncthreads();
  }

  // ---- epilogue ----
  int wo = wo0 + pb + r;
#pragma unroll
  for (int qq = 0; qq < 4; ++qq) {
    int o0 = ob + 4 * g + qq;
    int o1 = o0 + 16;
    out[((size_t)(b * COUT + o0) * HH + ho) * WW + wo] = acc0[qq] + bias[o0 & 63];
    out[((size_t)(b * COUT + o1) * HH + ho) * WW + wo] = acc1[qq] + bias[o1 & 63];
  }
}

extern "C" void kernel_launch(void* const* d_in, const int* in_sizes, int n_in,
                              void* d_out, int out_size, void* d_ws, size_t ws_size,
                              hipStream_t stream) {
  const float* x      = (const float*)d_in[0];
  const float* offset = (const float*)d_in[1];
  const float* weight = (const float*)d_in[2];
  const float* bias   = (const float*)d_in[3];
  float* out = (float*)d_out;

  const size_t xt_elems = (size_t)4 * NPIX * CIN;           // 8,388,608 bf16
  ushort_t* xtb = (ushort_t*)d_ws;
  ushort_t* wbf = (ushort_t*)((char*)d_ws + xt_elems * sizeof(ushort_t));

  prep_weight<<<(9 * 4096 + 255) / 256, 256, 0, stream>>>(weight, wbf);
  transpose_nchw_nhwc<<<dim3(512, 4, 4), dim3(32, 8), 0, stream>>>(x, (uint_t*)xtb);

  const int off_elems = 4 * 18 * NPIX;
  copy_offset<<<(off_elems / 4 + 255) / 256, 256, 0, stream>>>(
      (const float4*)offset, (float4*)(out + (size_t)4 * COUT * NPIX), off_elems / 4);

  deform_main<<<2048, 512, 0, stream>>>(xtb, offset, wbf, bias, out);
}